// Round 9
// baseline (760.155 us; speedup 1.0000x reference)
//
#include <hip/hip_runtime.h>

using half8   = __attribute__((ext_vector_type(8))) _Float16;
using floatx4 = __attribute__((ext_vector_type(4))) float;

namespace {
constexpr int S = 196, D = 512, C = 1006;
constexpr int CB  = 8;      // c per block -- FULL e=512 per block => tanh computed ONCE
constexpr int TPB = 512;    // 8 waves; wave wv = 64-wide e-slot
constexpr int RS  = 64;     // LDS row stride (halfs); 16B-seg XOR swizzle
constexpr int NPASS = 25;   // 24 x 8s + 1 x 4s = 196
constexpr float KTANH = 2.885390082f;   // 2/ln2, folded into word regs per chunk
constexpr float LOG2E = 1.44269504f;    // folded into W at prep: acc = log2e*feat

// r13 = r8's proven LDS discipline (bf via global_load_lds dbuf Wc, af via dbuf
// Tc, 1 barrier/chunk, 256-ish blocks = 1/CU, local softmax, no atomics) with
// the tanh DUPLICATION removed: r8's et-split made both e-halves compute the
// same T=tanh(img*word) tile (T is e-independent). Splitting c instead
// (CB=8, full e) halves tanh/thread 16->8 with MFMA/wave unchanged (32/chunk).
// M-frag packs 2s x 8c -> r11-proven shfl_xor(32) combine, no red buffer.
// Register law (r5/r6/r11/r12): bf frags must come from LDS, never held in
// registers across chunks -> per-chunk transients only, r8-like ~120 VGPR.

__device__ __forceinline__ int sw_off(int row, int seg) {
    return row * RS + ((seg ^ (row & 7)) << 3);
}

__device__ __forceinline__ void gload16(const _Float16* g, _Float16* l) {
    // async global->LDS, 16B/lane; LDS dest = wave-uniform base + lane*16
    __builtin_amdgcn_global_load_lds(
        (const __attribute__((address_space(1))) unsigned int*)g,
        (__attribute__((address_space(3))) unsigned int*)l, 16, 0, 0);
}

__device__ __forceinline__ _Float16 tanh_ps(float y) {
    // y = (2/ln2)*x; tanh(x) = 1 - 2/(exp2(y)+1); saturates correctly
    float e = __builtin_amdgcn_exp2f(y);
    return (_Float16)(1.0f - 2.0f * __builtin_amdgcn_rcpf(e + 1.0f));
}

__device__ __forceinline__ half8 tanh8(floatx4 i0, floatx4 i1, floatx4 w0, floatx4 w1) {
    half8 t;
    t[0] = tanh_ps(i0[0] * w0[0]); t[1] = tanh_ps(i0[1] * w0[1]);
    t[2] = tanh_ps(i0[2] * w0[2]); t[3] = tanh_ps(i0[3] * w0[3]);
    t[4] = tanh_ps(i1[0] * w1[0]); t[5] = tanh_ps(i1[1] * w1[1]);
    t[6] = tanh_ps(i1[2] * w1[2]); t[7] = tanh_ps(i1[3] * w1[3]);
    return t;
}

// Pre-swizzle fc3_w*log2e into the per-chunk image (8 chunks of 512 rows x 8
// 16B-segs, seg XOR row&7) -- exactly the LDS image the kernel DMAs (r8 verbatim).
__global__ void prep_w16sw(const float* __restrict__ fw, _Float16* __restrict__ W16sw) {
    int id = blockIdx.x * blockDim.x + threadIdx.x;    // 32768 segs
    int kki = id >> 12;
    int r   = (id >> 3) & 511;
    int j   = id & 7;
    const float* src = fw + (size_t)r * D + kki * 64 + j * 8;
    floatx4 v0 = *(const floatx4*)src;
    floatx4 v1 = *(const floatx4*)(src + 4);
    half8 h;
    h[0] = (_Float16)(v0[0] * LOG2E); h[1] = (_Float16)(v0[1] * LOG2E);
    h[2] = (_Float16)(v0[2] * LOG2E); h[3] = (_Float16)(v0[3] * LOG2E);
    h[4] = (_Float16)(v1[0] * LOG2E); h[5] = (_Float16)(v1[1] * LOG2E);
    h[6] = (_Float16)(v1[2] * LOG2E); h[7] = (_Float16)(v1[3] * LOG2E);
    *(half8*)&W16sw[((size_t)kki << 15) + r * RS + ((j ^ (r & 7)) << 3)] = h;
}

__global__ __launch_bounds__(TPB, 2) void semdec_mfma(
    const float* __restrict__ img, const float* __restrict__ word,
    const _Float16* __restrict__ W16sw, float* __restrict__ out)
{
    __shared__ __align__(16) _Float16 Wc[2][512 * RS];  // 2 x 64 KB (full e=512)
    __shared__ __align__(16) _Float16 Tc[2][64 * RS];   // 2 x 8 KB (64 m-rows x 64 k)
    // total 144 KB -> 1 block/CU (grid 252)

    const int ct = blockIdx.x;           // 0..125
    const int b  = blockIdx.y;           // 0..1

    const int tid  = threadIdx.x;
    const int lane = tid & 63;
    const int wv   = tid >> 6;           // 0..7 = e-slot (wv*64)
    const int l15  = lane & 15;
    const int quad = lane >> 4;

    const int c0 = ct * CB;

    // tanh map: wave wv owns s_local = wv; lane -> (ci = lane>>3, seg = lane&7)
    // Tc row m = s_local*8 + ci  (M-frag sp covers m in [sp*16, sp*16+16))
    const int ciT  = lane >> 3;          // 0..7
    const int segT = lane & 7;           // 0..7
    const int rowT = wv * 8 + ciT;       // 0..63
    int cgT = c0 + ciT; if (cgT > C - 1) cgT = C - 1;   // clamp pad c-rows
    const float* wordT = word + (size_t)cgT * D + segT * 8;
    const float* imgB  = img + (size_t)b * S * D;

    floatx4 lacc[4], aacc[4];            // per-(ej) softmax sums, this thread's s-subset
    #pragma unroll
    for (int ej = 0; ej < 4; ++ej) {
        lacc[ej] = (floatx4){0.f,0.f,0.f,0.f};
        aacc[ej] = (floatx4){0.f,0.f,0.f,0.f};
    }

    // ---- prologue: DMA W chunk 0 -> Wc[0]; tanh chunk 0 -> Tc[0]
    #pragma unroll
    for (int it = 0; it < 8; ++it) {
        int o = it * 4096 + wv * 512 + lane * 8;
        gload16(W16sw + o, &Wc[0][o]);
    }
    {
        const float* ip = &imgB[(size_t)wv * D + segT * 8];   // s_local=wv, chunk 0
        floatx4 i0 = *(const floatx4*)ip;
        floatx4 i1 = *(const floatx4*)(ip + 4);
        floatx4 w0 = *(const floatx4*)(wordT);
        floatx4 w1 = *(const floatx4*)(wordT + 4);
        w0 *= KTANH; w1 *= KTANH;
        *(half8*)&Tc[0][sw_off(rowT, segT)] = tanh8(i0, i1, w0, w1);
    }

    for (int pr = 0; pr < NPASS; ++pr) {
        floatx4 acc[4][4];   // [sp][ej] 64 AGPR; accumulates full K=512 per pass
        #pragma unroll
        for (int sp = 0; sp < 4; ++sp)
            #pragma unroll
            for (int ej = 0; ej < 4; ++ej)
                acc[sp][ej] = (floatx4){0.f,0.f,0.f,0.f};

        #pragma unroll
        for (int kk = 0; kk < 8; ++kk) {
            const int p   = kk & 1;
            const int lin = pr * 8 + kk;
            __syncthreads();  // Wc[p] DMA drained; Tc[p] visible; [p^1] readers done

            // --- DMA W chunk (kk+1)&7 -> Wc[p^1]; drains at NEXT barrier,
            //     covered by this chunk's tanh + 32 MFMA (cyclic W image)
            if (lin != NPASS * 8 - 1) {
                const _Float16* wg = W16sw + ((size_t)((kk + 1) & 7) << 15);
                #pragma unroll
                for (int it = 0; it < 8; ++it) {
                    int o = it * 4096 + wv * 512 + lane * 8;
                    gload16(wg + o, &Wc[p ^ 1][o]);
                }
            }

            // --- tanh inputs for chunk lin+1 (global; L1/L2-hot; consumed below)
            const int tl = lin + 1;
            const bool dot = (tl < NPASS * 8);
            floatx4 ti0, ti1, tw0, tw1;
            if (dot) {
                const int tkk = tl & 7;
                int srow = (tl >> 3) * 8 + wv; if (srow > S - 1) srow = S - 1;
                const float* ip = &imgB[(size_t)srow * D + tkk * 64 + segT * 8];
                ti0 = *(const floatx4*)ip;
                ti1 = *(const floatx4*)(ip + 4);
                tw0 = *(const floatx4*)(wordT + tkk * 64);
                tw1 = *(const floatx4*)(wordT + tkk * 64 + 4);
            }

            // --- k2=0: frags + 16 MFMA (transient bf/af only: no cross-chunk regs)
            {
                half8 bf[4], af[4];
                #pragma unroll
                for (int ej = 0; ej < 4; ++ej)
                    bf[ej] = *(const half8*)&Wc[p][sw_off(wv * 64 + ej * 16 + l15, quad)];
                #pragma unroll
                for (int sp = 0; sp < 4; ++sp)
                    af[sp] = *(const half8*)&Tc[p][sw_off(sp * 16 + l15, quad)];
                #pragma unroll
                for (int sp = 0; sp < 4; ++sp)
                    #pragma unroll
                    for (int ej = 0; ej < 4; ++ej)
                        acc[sp][ej] = __builtin_amdgcn_mfma_f32_16x16x32_f16(
                            af[sp], bf[ej], acc[sp][ej], 0, 0, 0);
            }

            // --- tanh chunk lin+1 -> Tc[p^1] (8 tanh/thread; overlaps matrix pipe)
            if (dot) {
                tw0 *= KTANH; tw1 *= KTANH;
                *(half8*)&Tc[p ^ 1][sw_off(rowT, segT)] = tanh8(ti0, ti1, tw0, tw1);
            }

            // --- k2=1: frags + 16 MFMA
            {
                half8 bf[4], af[4];
                #pragma unroll
                for (int ej = 0; ej < 4; ++ej)
                    bf[ej] = *(const half8*)&Wc[p][sw_off(wv * 64 + ej * 16 + l15, 4 + quad)];
                #pragma unroll
                for (int sp = 0; sp < 4; ++sp)
                    af[sp] = *(const half8*)&Tc[p][sw_off(sp * 16 + l15, 4 + quad)];
                #pragma unroll
                for (int sp = 0; sp < 4; ++sp)
                    #pragma unroll
                    for (int ej = 0; ej < 4; ++ej)
                        acc[sp][ej] = __builtin_amdgcn_mfma_f32_16x16x32_f16(
                            af[sp], bf[ej], acc[sp][ej], 0, 0, 0);
            }
        }

        // --- pass epilogue: online softmax accumulate (acc = log2e*feat).
        //     D-decode within frag sp: m = sp*16 + quad*4 + r ->
        //     s_local = sp*2 + (quad>>1), ci = (quad&1)*4 + r.
        const int s0 = pr * 8;
        #pragma unroll
        for (int sp = 0; sp < 4; ++sp) {
            const int srow = s0 + sp * 2 + (quad >> 1);
            if (srow < S) {
                #pragma unroll
                for (int ej = 0; ej < 4; ++ej) {
                    float ie = imgB[(size_t)srow * D + wv * 64 + ej * 16 + l15];
                    #pragma unroll
                    for (int r = 0; r < 4; ++r) {
                        float ev = __builtin_amdgcn_exp2f(acc[sp][ej][r]);
                        lacc[ej][r] += ev;
                        aacc[ej][r] += ie * ev;
                    }
                }
            }
        }
    }

    // --- combine the two s-parities: lane^32 flips quad bit1 = s_local parity;
    //     threads quad and quad^2 hold complementary s-subsets of the SAME (c,e).
    #pragma unroll
    for (int ej = 0; ej < 4; ++ej)
        #pragma unroll
        for (int r = 0; r < 4; ++r) {
            float lv = lacc[ej][r], av = aacc[ej][r];
            lacc[ej][r] = lv + __shfl_xor(lv, 32);
            aacc[ej][r] = av + __shfl_xor(av, 32);
        }

    // --- writeout: quad<2 owns; c = c0 + quad*4 + r, e = wv*64 + ej*16 + l15
    if (quad < 2) {
        #pragma unroll
        for (int r = 0; r < 4; ++r) {
            const int cg = c0 + quad * 4 + r;
            if (cg < C) {
                #pragma unroll
                for (int ej = 0; ej < 4; ++ej) {
                    const int eg = wv * 64 + ej * 16 + l15;
                    out[((size_t)b * C + cg) * D + eg] = aacc[ej][r] / lacc[ej][r];
                }
            }
        }
    }
}

} // namespace

extern "C" void kernel_launch(void* const* d_in, const int* in_sizes, int n_in,
                              void* d_out, int out_size, void* d_ws, size_t ws_size,
                              hipStream_t stream) {
    const float* img  = (const float*)d_in[0];
    const float* word = (const float*)d_in[1];
    const float* fw   = (const float*)d_in[2];
    // d_in[3] = fc3_b: constant over softmax axis s -> cancels exactly.
    float* out = (float*)d_out;

    _Float16* W16sw = (_Float16*)d_ws;   // 512 KB; only workspace use

    hipLaunchKernelGGL(prep_w16sw, dim3(128), dim3(256), 0, stream, fw, W16sw);
    hipLaunchKernelGGL(semdec_mfma, dim3(126, 2), dim3(TPB), 0, stream,
                       img, word, W16sw, out);
}

// Round 10
// 593.843 us; speedup vs baseline: 1.2801x; 1.2801x over previous
//
#include <hip/hip_runtime.h>

using half4   = __attribute__((ext_vector_type(4))) _Float16;
using half8   = __attribute__((ext_vector_type(8))) _Float16;
using floatx4 = __attribute__((ext_vector_type(4))) float;

namespace {
constexpr int S = 196, D = 512, C = 1006;
constexpr int CB  = 8;      // c per block; full e=512 => tanh computed exactly ONCE
constexpr int TPB = 512;    // 8 waves = 8 e-slots of 64
constexpr int RS  = 64;     // LDS row stride (halfs); 16B-seg XOR swizzle
constexpr int NPASS = 49;   // 49 x 4 s-rows = 196 exactly (no tail)
constexpr float KTANH = 2.885390082f;   // 2/ln2, folded into word regs per chunk
constexpr float LOG2E = 1.44269504f;    // folded into W at prep: acc = log2e*feat

// r14: duplication-free with LOWER register pressure than r8.
//  - Block = (b, 8-c tile, FULL e=512) over all S: softmax local, no atomics.
//  - 4 s-rows per pass -> M-tile 4s x 8c = 32 rows = 2 af frags:
//    acc[2][4]=32 AGPR (r8: 64), transients bf[4]+af[2]=48 (r8: 64).
//    Register law (r5/r6/r11/r12/r13): arch VGPR must stay ~<=110; this is
//    the first duplication-free shape that REDUCES state vs the clean r8.
//  - tanh: 2048/chunk = 4/thread (r8: 16 incl. et-duplication). Total = S*C*D once.
//  - W via r8's proven global_load_lds dbuf (full-e 64 KB chunks); af via dbuf
//    Tc (4 KB); img read from global (wave-uniform rows, L1/L2-hot; r12-proven).
//  - s-parity combine: frag packs 2s x 8c -> shfl_xor(32) + quad<2 write (r11-proven).

__device__ __forceinline__ int sw_off(int row, int seg) {
    return row * RS + ((seg ^ (row & 7)) << 3);
}

__device__ __forceinline__ void gload16(const _Float16* g, _Float16* l) {
    __builtin_amdgcn_global_load_lds(
        (const __attribute__((address_space(1))) unsigned int*)g,
        (__attribute__((address_space(3))) unsigned int*)l, 16, 0, 0);
}

__device__ __forceinline__ _Float16 tanh_ps(float y) {
    // y = (2/ln2)*x; tanh(x) = 1 - 2/(exp2(y)+1); saturates correctly
    float e = __builtin_amdgcn_exp2f(y);
    return (_Float16)(1.0f - 2.0f * __builtin_amdgcn_rcpf(e + 1.0f));
}

// Pre-swizzle fc3_w*log2e into the per-chunk image (8 chunks of 512 rows x 8
// 16B-segs, seg XOR row&7) -- exactly the LDS image the kernel DMAs (r8 verbatim).
__global__ void prep_w16sw(const float* __restrict__ fw, _Float16* __restrict__ W16sw) {
    int id = blockIdx.x * blockDim.x + threadIdx.x;    // 32768 segs
    int kki = id >> 12;
    int r   = (id >> 3) & 511;
    int j   = id & 7;
    const float* src = fw + (size_t)r * D + kki * 64 + j * 8;
    floatx4 v0 = *(const floatx4*)src;
    floatx4 v1 = *(const floatx4*)(src + 4);
    half8 h;
    h[0] = (_Float16)(v0[0] * LOG2E); h[1] = (_Float16)(v0[1] * LOG2E);
    h[2] = (_Float16)(v0[2] * LOG2E); h[3] = (_Float16)(v0[3] * LOG2E);
    h[4] = (_Float16)(v1[0] * LOG2E); h[5] = (_Float16)(v1[1] * LOG2E);
    h[6] = (_Float16)(v1[2] * LOG2E); h[7] = (_Float16)(v1[3] * LOG2E);
    *(half8*)&W16sw[((size_t)kki << 15) + r * RS + ((j ^ (r & 7)) << 3)] = h;
}

__global__ __launch_bounds__(TPB, 2) void semdec_mfma(
    const float* __restrict__ img, const float* __restrict__ word,
    const _Float16* __restrict__ W16sw, float* __restrict__ out)
{
    __shared__ __align__(16) _Float16 Wc[2][512 * RS];  // 2 x 64 KB (full e)
    __shared__ __align__(16) _Float16 Tc[2][32 * RS];   // 2 x 4 KB (32 m-rows x 64 k)
    // total 136 KB -> 1 block/CU (grid 252)

    const int ct = blockIdx.x;           // 0..125
    const int b  = blockIdx.y;           // 0..1

    const int tid  = threadIdx.x;
    const int lane = tid & 63;
    const int wv   = tid >> 6;           // 0..7 = e-slot (wv*64)
    const int l15  = lane & 15;
    const int quad = lane >> 4;

    const int c0 = ct * CB;

    // tanh map: thread -> (sT = tid>>7 in 0..3, ciT = (tid>>4)&7, segT = tid&15)
    // Tc row = sT*8 + ciT; k-slot = segT*4 halfs (4 tanh/thread/chunk)
    const int sT   = tid >> 7;
    const int ciT  = (tid >> 4) & 7;
    const int segT = tid & 15;
    const int rowT = sT * 8 + ciT;       // 0..31
    // swizzled b64 write offset: 16B-seg = segT>>1, low-half offset (segT&1)*4
    const int tcOff = rowT * RS + ((((segT >> 1) ^ (rowT & 7)) << 3) | ((segT & 1) << 2));
    int cgT = c0 + ciT; if (cgT > C - 1) cgT = C - 1;   // clamp pad c-rows
    const float* wordT = word + (size_t)cgT * D + segT * 4;
    const float* imgB  = img + (size_t)b * S * D;

    floatx4 lacc[4], aacc[4];            // softmax sums; thread owns (c,e) x s-parity
    #pragma unroll
    for (int ej = 0; ej < 4; ++ej) {
        lacc[ej] = (floatx4){0.f,0.f,0.f,0.f};
        aacc[ej] = (floatx4){0.f,0.f,0.f,0.f};
    }

    // ---- prologue: DMA W chunk 0 -> Wc[0]; tanh chunk 0 -> Tc[0]
    #pragma unroll
    for (int it = 0; it < 8; ++it) {
        int o = it * 4096 + wv * 512 + lane * 8;
        gload16(W16sw + o, &Wc[0][o]);
    }
    {
        floatx4 ti = *(const floatx4*)&imgB[(size_t)sT * D + segT * 4];
        floatx4 w  = *(const floatx4*)(wordT);
        w *= KTANH;
        half4 t;
        t[0] = tanh_ps(ti[0]*w[0]); t[1] = tanh_ps(ti[1]*w[1]);
        t[2] = tanh_ps(ti[2]*w[2]); t[3] = tanh_ps(ti[3]*w[3]);
        *(half4*)&Tc[0][tcOff] = t;
    }

    for (int pr = 0; pr < NPASS; ++pr) {
        floatx4 acc[2][4];   // [sp][ej] 32 AGPR
        #pragma unroll
        for (int sp = 0; sp < 2; ++sp)
            #pragma unroll
            for (int ej = 0; ej < 4; ++ej)
                acc[sp][ej] = (floatx4){0.f,0.f,0.f,0.f};

        #pragma unroll
        for (int kk = 0; kk < 8; ++kk) {
            const int p   = kk & 1;
            const int lin = pr * 8 + kk;
            __syncthreads();  // Wc[p] DMA drained; Tc[p] visible; [p^1] readers done

            // --- DMA W chunk (kk+1)&7 -> Wc[p^1]; drains at NEXT barrier (cyclic)
            if (lin != NPASS * 8 - 1) {
                const _Float16* wg = W16sw + ((size_t)((kk + 1) & 7) << 15);
                #pragma unroll
                for (int it = 0; it < 8; ++it) {
                    int o = it * 4096 + wv * 512 + lane * 8;
                    gload16(wg + o, &Wc[p ^ 1][o]);
                }
            }

            // --- tanh inputs for chunk lin+1 (global, wave-uniform row, L1/L2-hot)
            const int tl = lin + 1;
            const bool dot = (tl < NPASS * 8);
            floatx4 ti, tw;
            if (dot) {
                const int tkk = tl & 7;
                const int srow = (tl >> 3) * 4 + sT;        // < 196 by construction
                ti = *(const floatx4*)&imgB[(size_t)srow * D + tkk * 64 + segT * 4];
                tw = *(const floatx4*)(wordT + tkk * 64);
            }

            // --- k2=0: frags + 8 MFMA (transients only)
            {
                half8 bf[4], af[2];
                #pragma unroll
                for (int ej = 0; ej < 4; ++ej)
                    bf[ej] = *(const half8*)&Wc[p][sw_off(wv * 64 + ej * 16 + l15, quad)];
                #pragma unroll
                for (int sp = 0; sp < 2; ++sp)
                    af[sp] = *(const half8*)&Tc[p][sw_off(sp * 16 + l15, quad)];
                #pragma unroll
                for (int sp = 0; sp < 2; ++sp)
                    #pragma unroll
                    for (int ej = 0; ej < 4; ++ej)
                        acc[sp][ej] = __builtin_amdgcn_mfma_f32_16x16x32_f16(
                            af[sp], bf[ej], acc[sp][ej], 0, 0, 0);
            }

            // --- tanh chunk lin+1 -> Tc[p^1] (4 tanh/thread; overlaps matrix pipe)
            if (dot) {
                tw *= KTANH;
                half4 t;
                t[0] = tanh_ps(ti[0]*tw[0]); t[1] = tanh_ps(ti[1]*tw[1]);
                t[2] = tanh_ps(ti[2]*tw[2]); t[3] = tanh_ps(ti[3]*tw[3]);
                *(half4*)&Tc[p ^ 1][tcOff] = t;
            }

            // --- k2=1: frags + 8 MFMA
            {
                half8 bf[4], af[2];
                #pragma unroll
                for (int ej = 0; ej < 4; ++ej)
                    bf[ej] = *(const half8*)&Wc[p][sw_off(wv * 64 + ej * 16 + l15, 4 + quad)];
                #pragma unroll
                for (int sp = 0; sp < 2; ++sp)
                    af[sp] = *(const half8*)&Tc[p][sw_off(sp * 16 + l15, 4 + quad)];
                #pragma unroll
                for (int sp = 0; sp < 2; ++sp)
                    #pragma unroll
                    for (int ej = 0; ej < 4; ++ej)
                        acc[sp][ej] = __builtin_amdgcn_mfma_f32_16x16x32_f16(
                            af[sp], bf[ej], acc[sp][ej], 0, 0, 0);
            }
        }

        // --- pass epilogue: online softmax accumulate (acc = log2e*feat).
        //     Frag sp rows: m = quad*4+r -> s = pr*4 + sp*2 + (quad>>1),
        //     ci = (quad&1)*4 + r; col -> e = wv*64 + ej*16 + l15.
        const int s0 = pr * 4;
        #pragma unroll
        for (int sp = 0; sp < 2; ++sp) {
            const int srow = s0 + sp * 2 + (quad >> 1);     // always < 196
            #pragma unroll
            for (int ej = 0; ej < 4; ++ej) {
                float ie = imgB[(size_t)srow * D + wv * 64 + ej * 16 + l15];
                #pragma unroll
                for (int r = 0; r < 4; ++r) {
                    float ev = __builtin_amdgcn_exp2f(acc[sp][ej][r]);
                    lacc[ej][r] += ev;
                    aacc[ej][r] += ie * ev;
                }
            }
        }
    }

    // --- combine s-parities: lane^32 flips quad bit1 (the s-parity bit);
    //     threads quad, quad^2 hold complementary s-subsets of the SAME (c,e).
    #pragma unroll
    for (int ej = 0; ej < 4; ++ej)
        #pragma unroll
        for (int r = 0; r < 4; ++r) {
            float lv = lacc[ej][r], av = aacc[ej][r];
            lacc[ej][r] = lv + __shfl_xor(lv, 32);
            aacc[ej][r] = av + __shfl_xor(av, 32);
        }

    // --- writeout: quad<2 owns; c = c0 + quad*4 + r, e = wv*64 + ej*16 + l15
    if (quad < 2) {
        #pragma unroll
        for (int r = 0; r < 4; ++r) {
            const int cg = c0 + quad * 4 + r;
            if (cg < C) {
                #pragma unroll
                for (int ej = 0; ej < 4; ++ej) {
                    const int eg = wv * 64 + ej * 16 + l15;
                    out[((size_t)b * C + cg) * D + eg] = aacc[ej][r] / lacc[ej][r];
                }
            }
        }
    }
}

} // namespace

extern "C" void kernel_launch(void* const* d_in, const int* in_sizes, int n_in,
                              void* d_out, int out_size, void* d_ws, size_t ws_size,
                              hipStream_t stream) {
    const float* img  = (const float*)d_in[0];
    const float* word = (const float*)d_in[1];
    const float* fw   = (const float*)d_in[2];
    // d_in[3] = fc3_b: constant over softmax axis s -> cancels exactly.
    float* out = (float*)d_out;

    _Float16* W16sw = (_Float16*)d_ws;   // 512 KB; only workspace use

    hipLaunchKernelGGL(prep_w16sw, dim3(128), dim3(256), 0, stream, fw, W16sw);
    hipLaunchKernelGGL(semdec_mfma, dim3(126, 2), dim3(TPB), 0, stream,
                       img, word, W16sw, out);
}

// Round 11
// 354.047 us; speedup vs baseline: 2.1470x; 1.6773x over previous
//
#include <hip/hip_runtime.h>

using half8   = __attribute__((ext_vector_type(8))) _Float16;
using floatx4 = __attribute__((ext_vector_type(4))) float;

namespace {
constexpr int S = 196, D = 512, C = 1006;
constexpr int CB  = 8;       // c per block; FULL e=512 => tanh computed exactly once
constexpr int TPB = 768;     // 12 waves: 8 consumer (MFMA) + 4 producer (tanh/DMA)
constexpr int RS  = 64;      // LDS row stride (halfs); 16B-seg XOR swizzle
constexpr int NPASS  = 25;   // 24x8 + 1x4 s-rows = 196
constexpr int NCHUNK = 200;  // NPASS * 8 k-chunks of 64
constexpr float KTANH = 2.885390082f;   // 2/ln2, folded into word regs
constexpr float LOG2E = 1.44269504f;    // folded into W at prep: acc = log2e*feat

// r15: producer/consumer wave specialization. r14 (clean, no spill) proved the
// wall is a ~3.4k-cy fixed cost per barrier-chunk with SYMMETRIC waves: each
// chunk serializes ds_read -> MFMA -> tanh -> barrier -> DMA-drain (r8's
// MfmaUtil+VALUBusy ~= 80% SUM = lockstep phases). m114: an MFMA-only wave and
// a VALU-only wave on one CU overlap fully. So: 8 MFMA-only waves (2/SIMD) +
// 4 tanh/DMA waves (1/SIMD). Producers run the whole staging pipeline one
// chunk ahead; consumers only ds_read + MFMA (setprio(1) around the cluster,
// T5: pays exactly when wave roles diverge). One barrier per chunk.
// Register law (r5/r6/r11/r12/r13): consumer ~140 regs incl. acc, producer
// ~50; launch_bounds(768,3) caps at 170 -> no spill predicted. LDS 144 KB.

__device__ __forceinline__ int sw_off(int row, int seg) {
    return row * RS + ((seg ^ (row & 7)) << 3);
}

__device__ __forceinline__ void gload16(const _Float16* g, _Float16* l) {
    // async global->LDS, 16B/lane; LDS dest = wave-uniform base + lane*16
    __builtin_amdgcn_global_load_lds(
        (const __attribute__((address_space(1))) unsigned int*)g,
        (__attribute__((address_space(3))) unsigned int*)l, 16, 0, 0);
}

__device__ __forceinline__ _Float16 tanh_ps(float y) {
    // y = (2/ln2)*x; tanh(x) = 1 - 2/(exp2(y)+1); saturates correctly
    float e = __builtin_amdgcn_exp2f(y);
    return (_Float16)(1.0f - 2.0f * __builtin_amdgcn_rcpf(e + 1.0f));
}

// Pre-swizzle fc3_w*log2e into the per-chunk image (8 chunks of 512 rows x 8
// 16B-segs, seg XOR row&7) -- exactly the LDS image the kernel DMAs (r8-proven).
__global__ void prep_w16sw(const float* __restrict__ fw, _Float16* __restrict__ W16sw) {
    int id = blockIdx.x * blockDim.x + threadIdx.x;    // 32768 segs
    int kki = id >> 12;
    int r   = (id >> 3) & 511;
    int j   = id & 7;
    const float* src = fw + (size_t)r * D + kki * 64 + j * 8;
    floatx4 v0 = *(const floatx4*)src;
    floatx4 v1 = *(const floatx4*)(src + 4);
    half8 h;
    h[0] = (_Float16)(v0[0] * LOG2E); h[1] = (_Float16)(v0[1] * LOG2E);
    h[2] = (_Float16)(v0[2] * LOG2E); h[3] = (_Float16)(v0[3] * LOG2E);
    h[4] = (_Float16)(v1[0] * LOG2E); h[5] = (_Float16)(v1[1] * LOG2E);
    h[6] = (_Float16)(v1[2] * LOG2E); h[7] = (_Float16)(v1[3] * LOG2E);
    *(half8*)&W16sw[((size_t)kki << 15) + r * RS + ((j ^ (r & 7)) << 3)] = h;
}

__global__ __launch_bounds__(TPB, 3) void semdec_mfma(
    const float* __restrict__ img, const float* __restrict__ word,
    const _Float16* __restrict__ W16sw, float* __restrict__ out)
{
    __shared__ __align__(16) _Float16 Wc[2][512 * RS];  // 2 x 64 KB (full e)
    __shared__ __align__(16) _Float16 Tc[2][64 * RS];   // 2 x 8 KB (64 m-rows)
    // total 144 KB -> 1 block/CU (grid 252)

    const int ct = blockIdx.x;           // 0..125
    const int b  = blockIdx.y;           // 0..1
    const int tid  = threadIdx.x;
    const int lane = tid & 63;
    const int wv   = tid >> 6;           // 0..11
    const int c0   = ct * CB;
    const float* imgB = img + (size_t)b * S * D;

    if (wv >= 8) {
        // ================= PRODUCER waves (tanh + DMA), 1 per SIMD ============
        const int tidT = tid - 512;                 // 0..255
        const int sT   = tidT >> 5;                 // s-row 0..7 of the pass
        const int ciT  = (tidT >> 2) & 7;           // c 0..7
        const int ksl  = tidT & 3;                  // k-slot of 16 halfs
        const int rowT = sT * 8 + ciT;              // Tc row 0..63
        int cgT = c0 + ciT; if (cgT > C - 1) cgT = C - 1;
        const float* wordT = word + (size_t)cgT * D + ksl * 16;
        const int seg0 = ksl * 2;
        const int off0 = sw_off(rowT, seg0);
        const int off1 = sw_off(rowT, seg0 + 1);

        // prologue: DMA W chunk 0 -> Wc[0]; tanh chunk 0 -> Tc[0]
        #pragma unroll
        for (int it = 0; it < 16; ++it) {
            int o = (it * 256 + tidT) * 8;
            gload16(W16sw + o, &Wc[0][o]);
        }
        {
            const float* ip = &imgB[(size_t)sT * D + ksl * 16];
            floatx4 iv[4], wz[4];
            #pragma unroll
            for (int j = 0; j < 4; ++j) {
                iv[j] = *(const floatx4*)(ip + j * 4);
                wz[j] = *(const floatx4*)(wordT + j * 4) * KTANH;
            }
            half8 t0, t1;
            #pragma unroll
            for (int j = 0; j < 8; ++j) {
                t0[j] = tanh_ps(iv[j >> 2][j & 3] * wz[j >> 2][j & 3]);
                t1[j] = tanh_ps(iv[2 + (j >> 2)][j & 3] * wz[2 + (j >> 2)][j & 3]);
            }
            *(half8*)&Tc[0][off0] = t0;
            *(half8*)&Tc[0][off1] = t1;
        }

        for (int lin = 0; lin < NCHUNK; ++lin) {
            __syncthreads();  // consumers start chunk lin; we produce lin+1
            const int tl = lin + 1;
            if (tl < NCHUNK) {
                const int pn = tl & 1;
                // DMA W chunk (tl&7) -> Wc[pn]; drains at our next barrier wait
                const _Float16* wg = W16sw + ((size_t)(tl & 7) << 15);
                #pragma unroll
                for (int it = 0; it < 16; ++it) {
                    int o = (it * 256 + tidT) * 8;
                    gload16(wg + o, &Wc[pn][o]);
                }
                // tanh chunk tl -> Tc[pn]
                const int tkk = tl & 7;
                int srow = (tl >> 3) * 8 + sT; if (srow > S - 1) srow = S - 1;
                const float* ip = &imgB[(size_t)srow * D + tkk * 64 + ksl * 16];
                floatx4 iv[4], wz[4];
                #pragma unroll
                for (int j = 0; j < 4; ++j) {
                    iv[j] = *(const floatx4*)(ip + j * 4);
                    wz[j] = *(const floatx4*)(wordT + tkk * 64 + j * 4) * KTANH;
                }
                half8 t0, t1;
                #pragma unroll
                for (int j = 0; j < 8; ++j) {
                    t0[j] = tanh_ps(iv[j >> 2][j & 3] * wz[j >> 2][j & 3]);
                    t1[j] = tanh_ps(iv[2 + (j >> 2)][j & 3] * wz[2 + (j >> 2)][j & 3]);
                }
                *(half8*)&Tc[pn][off0] = t0;
                *(half8*)&Tc[pn][off1] = t1;
            }
        }
    } else {
        // ================= CONSUMER waves (MFMA + softmax), 2 per SIMD ========
        const int l15  = lane & 15;
        const int quad = lane >> 4;

        floatx4 lacc[4], aacc[4];
        #pragma unroll
        for (int ej = 0; ej < 4; ++ej) {
            lacc[ej] = (floatx4){0.f,0.f,0.f,0.f};
            aacc[ej] = (floatx4){0.f,0.f,0.f,0.f};
        }

        for (int pr = 0; pr < NPASS; ++pr) {
            floatx4 acc[4][4];   // [sp][ej] 64 AGPR
            #pragma unroll
            for (int sp = 0; sp < 4; ++sp)
                #pragma unroll
                for (int ej = 0; ej < 4; ++ej)
                    acc[sp][ej] = (floatx4){0.f,0.f,0.f,0.f};

            for (int kk = 0; kk < 8; ++kk) {
                __syncthreads();  // Wc[p]/Tc[p] produced last chunk now visible
                const int p = kk & 1;          // lin = pr*8+kk, pr*8 even
                const _Float16* Wp = Wc[p];
                const _Float16* Tp = Tc[p];

                {   // k2 = 0
                    half8 bf[4], af[4];
                    #pragma unroll
                    for (int ej = 0; ej < 4; ++ej)
                        bf[ej] = *(const half8*)&Wp[sw_off(wv * 64 + ej * 16 + l15, quad)];
                    #pragma unroll
                    for (int sp = 0; sp < 4; ++sp)
                        af[sp] = *(const half8*)&Tp[sw_off(sp * 16 + l15, quad)];
                    __builtin_amdgcn_s_setprio(1);
                    #pragma unroll
                    for (int sp = 0; sp < 4; ++sp)
                        #pragma unroll
                        for (int ej = 0; ej < 4; ++ej)
                            acc[sp][ej] = __builtin_amdgcn_mfma_f32_16x16x32_f16(
                                af[sp], bf[ej], acc[sp][ej], 0, 0, 0);
                    __builtin_amdgcn_s_setprio(0);
                }
                {   // k2 = 1
                    half8 bf[4], af[4];
                    #pragma unroll
                    for (int ej = 0; ej < 4; ++ej)
                        bf[ej] = *(const half8*)&Wp[sw_off(wv * 64 + ej * 16 + l15, 4 + quad)];
                    #pragma unroll
                    for (int sp = 0; sp < 4; ++sp)
                        af[sp] = *(const half8*)&Tp[sw_off(sp * 16 + l15, 4 + quad)];
                    __builtin_amdgcn_s_setprio(1);
                    #pragma unroll
                    for (int sp = 0; sp < 4; ++sp)
                        #pragma unroll
                        for (int ej = 0; ej < 4; ++ej)
                            acc[sp][ej] = __builtin_amdgcn_mfma_f32_16x16x32_f16(
                                af[sp], bf[ej], acc[sp][ej], 0, 0, 0);
                    __builtin_amdgcn_s_setprio(0);
                }
            }

            // --- pass epilogue: online softmax (acc = log2e*feat -> exp2).
            //     Frag rows m = sp*16 + quad*4 + r -> s = pr*8 + sp*2 + (quad>>1),
            //     ci = (quad&1)*4 + r; cols -> e = wv*64 + ej*16 + l15.
            const int s0 = pr * 8;
            #pragma unroll
            for (int sp = 0; sp < 4; ++sp) {
                const int srow = s0 + sp * 2 + (quad >> 1);
                if (srow < S) {
                    #pragma unroll
                    for (int ej = 0; ej < 4; ++ej) {
                        float ie = imgB[(size_t)srow * D + wv * 64 + ej * 16 + l15];
                        #pragma unroll
                        for (int r = 0; r < 4; ++r) {
                            float ev = __builtin_amdgcn_exp2f(acc[sp][ej][r]);
                            lacc[ej][r] += ev;
                            aacc[ej][r] += ie * ev;
                        }
                    }
                }
            }
        }

        // --- combine s-parities: lane^32 flips quad bit1 (s-parity);
        //     quad and quad^2 hold complementary s-subsets of the SAME (c,e).
        #pragma unroll
        for (int ej = 0; ej < 4; ++ej)
            #pragma unroll
            for (int r = 0; r < 4; ++r) {
                float lv = lacc[ej][r], av = aacc[ej][r];
                lacc[ej][r] = lv + __shfl_xor(lv, 32);
                aacc[ej][r] = av + __shfl_xor(av, 32);
            }

        // --- writeout: quad<2 owns; c = c0 + quad*4 + r, e = wv*64 + ej*16 + l15
        if (quad < 2) {
            #pragma unroll
            for (int r = 0; r < 4; ++r) {
                const int cg = c0 + quad * 4 + r;
                if (cg < C) {
                    #pragma unroll
                    for (int ej = 0; ej < 4; ++ej) {
                        const int eg = wv * 64 + ej * 16 + l15;
                        out[((size_t)b * C + cg) * D + eg] = aacc[ej][r] / lacc[ej][r];
                    }
                }
            }
        }
    }
}

} // namespace

extern "C" void kernel_launch(void* const* d_in, const int* in_sizes, int n_in,
                              void* d_out, int out_size, void* d_ws, size_t ws_size,
                              hipStream_t stream) {
    const float* img  = (const float*)d_in[0];
    const float* word = (const float*)d_in[1];
    const float* fw   = (const float*)d_in[2];
    // d_in[3] = fc3_b: constant over softmax axis s -> cancels exactly.
    float* out = (float*)d_out;

    _Float16* W16sw = (_Float16*)d_ws;   // 512 KB; only workspace use

    hipLaunchKernelGGL(prep_w16sw, dim3(128), dim3(256), 0, stream, fw, W16sw);
    hipLaunchKernelGGL(semdec_mfma, dim3(126, 2), dim3(TPB), 0, stream,
                       img, word, W16sw, out);
}

// Round 12
// 335.722 us; speedup vs baseline: 2.2642x; 1.0546x over previous
//
#include <hip/hip_runtime.h>

using half8   = __attribute__((ext_vector_type(8))) _Float16;
using floatx4 = __attribute__((ext_vector_type(4))) float;

namespace {
constexpr int S = 196, D = 512, C = 1006;
constexpr int CB  = 8;       // c per block; FULL e=512 => tanh computed exactly once
constexpr int TPB = 768;     // 12 waves: 8 consumer (MFMA) + 4 producer (tanh/DMA)
constexpr int RS  = 64;      // LDS row stride (halfs); 16B-seg XOR swizzle
constexpr int NPASS  = 25;   // 24x8 + 1x4 s-rows = 196
constexpr int NCHUNK = 200;  // NPASS * 8 k-chunks of 64
constexpr float KTANH = 2.885390082f;   // 2/ln2, folded into word regs
constexpr float LOG2E = 1.44269504f;    // folded into W at prep: acc = log2e*feat

// r16 = r15 (clean producer/consumer, 344us) + two chunk-wall fixes:
//  (1) producer REG-HELD tanh inputs one chunk ahead: r15 issued DMA then
//      img/word loads then tanh -> compiler forced s_waitcnt vmcnt(0), i.e.
//      the full 64KB DMA drained BEFORE tanh started (serial). Now tanh
//      consumes regs drained by the previous barrier; DMA drains under it.
//  (2) per-block K-PHASE STAGGER: r8/r14/r15 all show a structure-independent
//      ~3.4-4.1k cy/chunk. All blocks, in lockstep, DMA the SAME 64KB W chunk
//      simultaneously -> 32 CUs/XCD hammer the same 1024 L2 lines (no
//      broadcast; bank-serialized). K-sum order is free: block processes
//      chunks ((kk + phase) & 7), phase=(bid>>3)&7 -> same-line concurrency /8.

__device__ __forceinline__ int sw_off(int row, int seg) {
    return row * RS + ((seg ^ (row & 7)) << 3);
}

__device__ __forceinline__ void gload16(const _Float16* g, _Float16* l) {
    // async global->LDS, 16B/lane; LDS dest = wave-uniform base + lane*16
    __builtin_amdgcn_global_load_lds(
        (const __attribute__((address_space(1))) unsigned int*)g,
        (__attribute__((address_space(3))) unsigned int*)l, 16, 0, 0);
}

__device__ __forceinline__ _Float16 tanh_ps(float y) {
    // y = (2/ln2)*x; tanh(x) = 1 - 2/(exp2(y)+1); saturates correctly
    float e = __builtin_amdgcn_exp2f(y);
    return (_Float16)(1.0f - 2.0f * __builtin_amdgcn_rcpf(e + 1.0f));
}

// Pre-swizzle fc3_w*log2e into the per-chunk image (8 chunks of 512 rows x 8
// 16B-segs, seg XOR row&7) -- exactly the LDS image the kernel DMAs (r8-proven).
__global__ void prep_w16sw(const float* __restrict__ fw, _Float16* __restrict__ W16sw) {
    int id = blockIdx.x * blockDim.x + threadIdx.x;    // 32768 segs
    int kki = id >> 12;
    int r   = (id >> 3) & 511;
    int j   = id & 7;
    const float* src = fw + (size_t)r * D + kki * 64 + j * 8;
    floatx4 v0 = *(const floatx4*)src;
    floatx4 v1 = *(const floatx4*)(src + 4);
    half8 h;
    h[0] = (_Float16)(v0[0] * LOG2E); h[1] = (_Float16)(v0[1] * LOG2E);
    h[2] = (_Float16)(v0[2] * LOG2E); h[3] = (_Float16)(v0[3] * LOG2E);
    h[4] = (_Float16)(v1[0] * LOG2E); h[5] = (_Float16)(v1[1] * LOG2E);
    h[6] = (_Float16)(v1[2] * LOG2E); h[7] = (_Float16)(v1[3] * LOG2E);
    *(half8*)&W16sw[((size_t)kki << 15) + r * RS + ((j ^ (r & 7)) << 3)] = h;
}

__global__ __launch_bounds__(TPB, 3) void semdec_mfma(
    const float* __restrict__ img, const float* __restrict__ word,
    const _Float16* __restrict__ W16sw, float* __restrict__ out)
{
    __shared__ __align__(16) _Float16 Wc[2][512 * RS];  // 2 x 64 KB (full e)
    __shared__ __align__(16) _Float16 Tc[2][64 * RS];   // 2 x 8 KB (64 m-rows)
    // total 144 KB -> 1 block/CU (grid 252)

    const int ct = blockIdx.x;           // 0..125
    const int b  = blockIdx.y;           // 0..1
    const int bid  = blockIdx.y * gridDim.x + blockIdx.x;
    const int phase = (bid >> 3) & 7;    // same-XCD neighbors get different phases
    const int tid  = threadIdx.x;
    const int lane = tid & 63;
    const int wv   = tid >> 6;           // 0..11
    const int c0   = ct * CB;
    const float* imgB = img + (size_t)b * S * D;

    if (wv >= 8) {
        // ================= PRODUCER waves (tanh + DMA), 1 per SIMD ============
        const int tidT = tid - 512;                 // 0..255
        const int sT   = tidT >> 5;                 // s-row 0..7 of the pass
        const int ciT  = (tidT >> 2) & 7;           // c 0..7
        const int ksl  = tidT & 3;                  // k-slot of 16 halfs
        const int rowT = sT * 8 + ciT;              // Tc row 0..63
        int cgT = c0 + ciT; if (cgT > C - 1) cgT = C - 1;
        const float* wordT = word + (size_t)cgT * D + ksl * 16;
        const int seg0 = ksl * 2;
        const int off0 = sw_off(rowT, seg0);
        const int off1 = sw_off(rowT, seg0 + 1);

        // ---- prologue: DMA W chunk kmap(0)=phase -> Wc[0]; tanh step 0 -> Tc[0];
        //      preload step-1 inputs into regs (drained by first barrier).
        {
            const _Float16* wg = W16sw + ((size_t)phase << 15);
            #pragma unroll
            for (int it = 0; it < 16; ++it) {
                int o = (it * 256 + tidT) * 8;
                gload16(wg + o, &Wc[0][o]);
            }
        }
        {
            const float* ip = &imgB[(size_t)sT * D + phase * 64 + ksl * 16];
            floatx4 iv0[4], wz0[4];
            #pragma unroll
            for (int j = 0; j < 4; ++j) {
                iv0[j] = *(const floatx4*)(ip + j * 4);
                wz0[j] = *(const floatx4*)(wordT + phase * 64 + j * 4) * KTANH;
            }
            half8 t0, t1;
            #pragma unroll
            for (int j = 0; j < 8; ++j) {
                t0[j] = tanh_ps(iv0[j >> 2][j & 3] * wz0[j >> 2][j & 3]);
                t1[j] = tanh_ps(iv0[2 + (j >> 2)][j & 3] * wz0[2 + (j >> 2)][j & 3]);
            }
            *(half8*)&Tc[0][off0] = t0;
            *(half8*)&Tc[0][off1] = t1;
        }
        floatx4 ivB[4], wzB[4];   // inputs for the NEXT produced step
        {
            const int kn1 = (1 + phase) & 7;        // step 1 (pass 0, same s-rows)
            const float* ip = &imgB[(size_t)sT * D + kn1 * 64 + ksl * 16];
            #pragma unroll
            for (int j = 0; j < 4; ++j) {
                ivB[j] = *(const floatx4*)(ip + j * 4);
                wzB[j] = *(const floatx4*)(wordT + kn1 * 64 + j * 4);
            }
        }

        for (int lin = 0; lin < NCHUNK; ++lin) {
            __syncthreads();  // consumers start step lin; our preloads are drained
            // rotate preloaded inputs into the consume slot (pure reg moves)
            floatx4 ivA[4], wzA[4];
            #pragma unroll
            for (int j = 0; j < 4; ++j) { ivA[j] = ivB[j]; wzA[j] = wzB[j]; }

            const int tl = lin + 1;
            if (tl < NCHUNK) {
                const int pn = tl & 1;
                const int kn = ((tl & 7) + phase) & 7;
                // --- DMA W chunk kn -> Wc[pn] (drains at our NEXT barrier,
                //     in parallel with the tanh below -- no vmcnt(0) before it)
                const _Float16* wg = W16sw + ((size_t)kn << 15);
                #pragma unroll
                for (int it = 0; it < 16; ++it) {
                    int o = (it * 256 + tidT) * 8;
                    gload16(wg + o, &Wc[pn][o]);
                }
                // --- preload inputs for step tl+1 (consumed next chunk)
                if (tl + 1 < NCHUNK) {
                    const int t2  = tl + 1;
                    const int kn2 = ((t2 & 7) + phase) & 7;
                    int srow = (t2 >> 3) * 8 + sT; if (srow > S - 1) srow = S - 1;
                    const float* ip = &imgB[(size_t)srow * D + kn2 * 64 + ksl * 16];
                    #pragma unroll
                    for (int j = 0; j < 4; ++j) {
                        ivB[j] = *(const floatx4*)(ip + j * 4);
                        wzB[j] = *(const floatx4*)(wordT + kn2 * 64 + j * 4);
                    }
                }
                // --- tanh step tl from HELD regs (starts immediately; overlaps DMA)
                half8 t0, t1;
                #pragma unroll
                for (int j = 0; j < 4; ++j) wzA[j] *= KTANH;
                #pragma unroll
                for (int j = 0; j < 8; ++j) {
                    t0[j] = tanh_ps(ivA[j >> 2][j & 3] * wzA[j >> 2][j & 3]);
                    t1[j] = tanh_ps(ivA[2 + (j >> 2)][j & 3] * wzA[2 + (j >> 2)][j & 3]);
                }
                *(half8*)&Tc[pn][off0] = t0;
                *(half8*)&Tc[pn][off1] = t1;
            }
        }
    } else {
        // ================= CONSUMER waves (MFMA + softmax), 2 per SIMD ========
        const int l15  = lane & 15;
        const int quad = lane >> 4;

        floatx4 lacc[4], aacc[4];
        #pragma unroll
        for (int ej = 0; ej < 4; ++ej) {
            lacc[ej] = (floatx4){0.f,0.f,0.f,0.f};
            aacc[ej] = (floatx4){0.f,0.f,0.f,0.f};
        }

        for (int pr = 0; pr < NPASS; ++pr) {
            floatx4 acc[4][4];   // [sp][ej] 64 AGPR
            #pragma unroll
            for (int sp = 0; sp < 4; ++sp)
                #pragma unroll
                for (int ej = 0; ej < 4; ++ej)
                    acc[sp][ej] = (floatx4){0.f,0.f,0.f,0.f};

            for (int kk = 0; kk < 8; ++kk) {
                __syncthreads();  // Wc[p]/Tc[p] produced last chunk now visible
                const int p = kk & 1;          // lin = pr*8+kk, pr*8 even
                const _Float16* Wp = Wc[p];
                const _Float16* Tp = Tc[p];

                {   // k2 = 0
                    half8 bf[4], af[4];
                    #pragma unroll
                    for (int ej = 0; ej < 4; ++ej)
                        bf[ej] = *(const half8*)&Wp[sw_off(wv * 64 + ej * 16 + l15, quad)];
                    #pragma unroll
                    for (int sp = 0; sp < 4; ++sp)
                        af[sp] = *(const half8*)&Tp[sw_off(sp * 16 + l15, quad)];
                    __builtin_amdgcn_s_setprio(1);
                    #pragma unroll
                    for (int sp = 0; sp < 4; ++sp)
                        #pragma unroll
                        for (int ej = 0; ej < 4; ++ej)
                            acc[sp][ej] = __builtin_amdgcn_mfma_f32_16x16x32_f16(
                                af[sp], bf[ej], acc[sp][ej], 0, 0, 0);
                    __builtin_amdgcn_s_setprio(0);
                }
                {   // k2 = 1
                    half8 bf[4], af[4];
                    #pragma unroll
                    for (int ej = 0; ej < 4; ++ej)
                        bf[ej] = *(const half8*)&Wp[sw_off(wv * 64 + ej * 16 + l15, 4 + quad)];
                    #pragma unroll
                    for (int sp = 0; sp < 4; ++sp)
                        af[sp] = *(const half8*)&Tp[sw_off(sp * 16 + l15, 4 + quad)];
                    __builtin_amdgcn_s_setprio(1);
                    #pragma unroll
                    for (int sp = 0; sp < 4; ++sp)
                        #pragma unroll
                        for (int ej = 0; ej < 4; ++ej)
                            acc[sp][ej] = __builtin_amdgcn_mfma_f32_16x16x32_f16(
                                af[sp], bf[ej], acc[sp][ej], 0, 0, 0);
                    __builtin_amdgcn_s_setprio(0);
                }
            }

            // --- pass epilogue: online softmax (acc = log2e*feat -> exp2).
            //     Frag rows m = sp*16 + quad*4 + r -> s = pr*8 + sp*2 + (quad>>1),
            //     ci = (quad&1)*4 + r; cols -> e = wv*64 + ej*16 + l15.
            //     (K-chunk stagger only permutes the summation order of acc.)
            const int s0 = pr * 8;
            #pragma unroll
            for (int sp = 0; sp < 4; ++sp) {
                const int srow = s0 + sp * 2 + (quad >> 1);
                if (srow < S) {
                    #pragma unroll
                    for (int ej = 0; ej < 4; ++ej) {
                        float ie = imgB[(size_t)srow * D + wv * 64 + ej * 16 + l15];
                        #pragma unroll
                        for (int r = 0; r < 4; ++r) {
                            float ev = __builtin_amdgcn_exp2f(acc[sp][ej][r]);
                            lacc[ej][r] += ev;
                            aacc[ej][r] += ie * ev;
                        }
                    }
                }
            }
        }

        // --- combine s-parities: lane^32 flips quad bit1 (s-parity);
        //     quad and quad^2 hold complementary s-subsets of the SAME (c,e).
        #pragma unroll
        for (int ej = 0; ej < 4; ++ej)
            #pragma unroll
            for (int r = 0; r < 4; ++r) {
                float lv = lacc[ej][r], av = aacc[ej][r];
                lacc[ej][r] = lv + __shfl_xor(lv, 32);
                aacc[ej][r] = av + __shfl_xor(av, 32);
            }

        // --- writeout: quad<2 owns; c = c0 + quad*4 + r, e = wv*64 + ej*16 + l15
        if (quad < 2) {
            #pragma unroll
            for (int r = 0; r < 4; ++r) {
                const int cg = c0 + quad * 4 + r;
                if (cg < C) {
                    #pragma unroll
                    for (int ej = 0; ej < 4; ++ej) {
                        const int eg = wv * 64 + ej * 16 + l15;
                        out[((size_t)b * C + cg) * D + eg] = aacc[ej][r] / lacc[ej][r];
                    }
                }
            }
        }
    }
}

} // namespace

extern "C" void kernel_launch(void* const* d_in, const int* in_sizes, int n_in,
                              void* d_out, int out_size, void* d_ws, size_t ws_size,
                              hipStream_t stream) {
    const float* img  = (const float*)d_in[0];
    const float* word = (const float*)d_in[1];
    const float* fw   = (const float*)d_in[2];
    // d_in[3] = fc3_b: constant over softmax axis s -> cancels exactly.
    float* out = (float*)d_out;

    _Float16* W16sw = (_Float16*)d_ws;   // 512 KB; only workspace use

    hipLaunchKernelGGL(prep_w16sw, dim3(128), dim3(256), 0, stream, fw, W16sw);
    hipLaunchKernelGGL(semdec_mfma, dim3(126, 2), dim3(TPB), 0, stream,
                       img, word, W16sw, out);
}